// Round 9
// baseline (949.545 us; speedup 1.0000x reference)
//
#include <hip/hip_runtime.h>

#define PW 90
#define IS2 0.70710678118654752f

__device__ __forceinline__ int symidx(int t, int n) {
    t = (t < 0) ? (-1 - t) : t;
    return (t >= n) ? (2 * n - 1 - t) : t;
}

#define SB() __builtin_amdgcn_sched_barrier(0)

// ================= border-path helpers (r1, proven) =================
__device__ __forceinline__ void col13_yl(
    float (&acc)[32], const float* __restrict__ ylp,
    const float* __restrict__ taps, int r0, int cc)
{
    #pragma unroll
    for (int pi = 0; pi < 44; ++pi) {
        int rr = symidx(r0 - 6 + pi, 256);
        float v = ylp[rr * 256 + cc];
        #pragma unroll
        for (int j = 0; j < 13; ++j) {
            int ro = pi + j - 12;
            if (ro >= 0 && ro < 32) acc[ro] = fmaf(taps[j], v, acc[ro]);
        }
    }
}

__device__ __forceinline__ void col13_c2q(
    float (&acc)[32], const float* __restrict__ yhr, const float* __restrict__ yhi,
    int bA, int bB, const float* __restrict__ taps, int r0, int cc)
{
    const int cp = cc & 1;
    const int j2 = cc >> 1;
    #pragma unroll
    for (int pi = 0; pi < 44; ++pi) {
        int rr = symidx(r0 - 6 + pi, 256);
        int rp = rr & 1;
        int i2 = rr >> 1;
        const float* base = (((rp ^ cp) != 0) ? yhi : yhr) + (i2 * 128 + j2);
        float A  = base[bA * 16384];
        float Bv = base[bB * 16384];
        float vA = (rp & cp)       ? -A  : A;
        float vB = (rp & (cp ^ 1)) ? -Bv : Bv;
        float v = (vA + vB) * IS2;
        #pragma unroll
        for (int j = 0; j < 13; ++j) {
            int ro = pi + j - 12;
            if (ro >= 0 && ro < 32) acc[ro] = fmaf(taps[j], v, acc[ro]);
        }
    }
}

__device__ __forceinline__ void col19_c2q(
    float (&acc)[32], const float* __restrict__ yhr, const float* __restrict__ yhi,
    const float* __restrict__ taps, int r0, int cc)
{
    const int bA = 0, bB = 5;
    const int cp = cc & 1;
    const int j2 = cc >> 1;
    #pragma unroll
    for (int pi = 0; pi < 50; ++pi) {
        int rr = symidx(r0 - 9 + pi, 256);
        int rp = rr & 1;
        int i2 = rr >> 1;
        const float* base = (((rp ^ cp) != 0) ? yhi : yhr) + (i2 * 128 + j2);
        float A  = base[bA * 16384];
        float Bv = base[bB * 16384];
        float vA = (rp & cp)       ? -A  : A;
        float vB = (rp & (cp ^ 1)) ? -Bv : Bv;
        float v = (vA + vB) * IS2;
        #pragma unroll
        for (int j = 0; j < 19; ++j) {
            int ro = pi + j - 18;
            if (ro >= 0 && ro < 32) acc[ro] = fmaf(taps[j], v, acc[ro]);
        }
    }
}

// ================= interior pipelined helpers (r8, proven) =================
template<int NU>
__device__ __forceinline__ void load_pairs(float (&buf)[28],
    const float* __restrict__ pEA, const float* __restrict__ pEB,
    const float* __restrict__ pOA, const float* __restrict__ pOB,
    int vof)
{
    #pragma unroll
    for (int u = 0; u < NU; ++u) {
        buf[4*u+0] = pEA[vof + u * 128];
        buf[4*u+1] = pEB[vof + u * 128];
        buf[4*u+2] = pOA[vof + u * 128];
        buf[4*u+3] = pOB[vof + u * 128];
    }
}

template<int L, int EPI0, int UB, int NU>
__device__ __forceinline__ void consume_pairs(float (&acc)[32], const float (&buf)[28],
                                              float sgn, const float* __restrict__ taps)
{
    #pragma unroll
    for (int u = 0; u < NU; ++u) {
        float ve = (buf[4*u+0] + buf[4*u+1]) * IS2;
        float vo = (buf[4*u+2] - buf[4*u+3]) * sgn;
        const int pi = EPI0 + 2 * (UB + u);
        #pragma unroll
        for (int j = 0; j < L; ++j) {
            int ro = pi + j - (L - 1);
            if (ro >= 0 && ro < 32) acc[ro] = fmaf(taps[j], ve, acc[ro]);
        }
        #pragma unroll
        for (int j = 0; j < L; ++j) {
            int ro = pi + 1 + j - (L - 1);
            if (ro >= 0 && ro < 32) acc[ro] = fmaf(taps[j], vo, acc[ro]);
        }
    }
}

template<int NT>
__device__ __forceinline__ void load_rows(float (&buf)[11], const float* __restrict__ p, int t0)
{
    #pragma unroll
    for (int t = 0; t < NT; ++t) buf[t] = p[(t0 + t) * 256];
}

template<int TB, int NT>
__device__ __forceinline__ void consume_rows(float (&acc)[32], const float (&buf)[11],
                                             const float* __restrict__ taps)
{
    #pragma unroll
    for (int t = 0; t < NT; ++t) {
        float v = buf[t];
        const int pi = TB + t;
        #pragma unroll
        for (int j = 0; j < 13; ++j) {
            int ro = pi + j - 12;
            if (ro >= 0 && ro < 32) acc[ro] = fmaf(taps[j], v, acc[ro]);
        }
    }
}

template<int L, int EPI0, int NPT, int C>
__device__ __forceinline__ void c2q_col_pipe(
    float (&acc)[32],
    const float* __restrict__ pEA, const float* __restrict__ pEB,
    const float* __restrict__ pOA, const float* __restrict__ pOB,
    int vof, float sgn, const float* __restrict__ taps)
{
    float bufA[28], bufB[28];
    constexpr int R = NPT - 3 * C;
    load_pairs<C>(bufA, pEA, pEB, pOA, pOB, vof);
    SB();
    load_pairs<C>(bufB, pEA, pEB, pOA, pOB, vof + C * 128);
    SB();
    consume_pairs<L, EPI0, 0, C>(acc, bufA, sgn, taps);
    SB();
    load_pairs<C>(bufA, pEA, pEB, pOA, pOB, vof + 2 * C * 128);
    SB();
    consume_pairs<L, EPI0, C, C>(acc, bufB, sgn, taps);
    SB();
    load_pairs<R>(bufB, pEA, pEB, pOA, pOB, vof + 3 * C * 128);
    SB();
    consume_pairs<L, EPI0, 2 * C, C>(acc, bufA, sgn, taps);
    SB();
    consume_pairs<L, EPI0, 3 * C, R>(acc, bufB, sgn, taps);
}

extern "C" __global__ __launch_bounds__(512, 8) void dtcwt_inv(
    const float* __restrict__ Yl, const float* __restrict__ Yhr,
    const float* __restrict__ Yhi,
    const float* __restrict__ g0, const float* __restrict__ g1,
    const float* __restrict__ g2, float* __restrict__ out)
{
    // sU[0] = t1a (+t1b added after barrier1), sU[1] = t2 (hl), sU[2] = t3 (hh)
    __shared__ __align__(16) float sU[3][32][PW];   // 34560 B -> 4 blocks/CU

    const int tid = threadIdx.x;
    // bijective XCD swizzle: 16384 = 8 x 2048
    const int wg  = blockIdx.x;
    const int swz = (wg & 7) * 2048 + (wg >> 3);
    const int plane = swz >> 5;
    const int bt = swz & 31;
    const int bx = bt & 3;
    const int by = bt >> 2;
    const int r0 = by * 32;
    const int c0 = bx * 64;

    const float* ylp = Yl  + (size_t)plane * 65536;
    const float* yhr = Yhr + (size_t)plane * 6 * 16384;
    const float* yhi = Yhi + (size_t)plane * 6 * 16384;

    const bool rowInterior = (by >= 1) && (by <= 6);

    const int role = tid >> 7;
    const int lr   = tid & 127;

    float acc[32];
    #pragma unroll
    for (int i = 0; i < 32; ++i) acc[i] = 0.0f;
    int ti = -1;

    if (rowInterior) {
        if (role == 0) {
            if (lr < 76) {
                ti = lr + 6;
                int cc = symidx(c0 + lr - 6, 256);
                const float* p = ylp + (r0 - 6) * 256 + cc;
                float bufA[11], bufB[11];
                load_rows<11>(bufA, p, 0);
                SB();
                load_rows<11>(bufB, p, 11);
                SB();
                consume_rows<0, 11>(acc, bufA, g0);
                SB();
                load_rows<11>(bufA, p, 22);
                SB();
                consume_rows<11, 11>(acc, bufB, g0);
                SB();
                load_rows<11>(bufB, p, 33);
                SB();
                consume_rows<22, 11>(acc, bufA, g0);
                SB();
                consume_rows<33, 11>(acc, bufB, g0);
            }
        } else if (role == 1) {
            if (lr < 76) {                        // t1b = col_g1(lh), bands 0,5
                ti = lr + 6;
                int cc = symidx(c0 + lr - 6, 256);
                int cp = cc & 1, j2 = cc >> 1;
                const float* pE = cp ? yhi : yhr;
                const float* pO = cp ? yhr : yhi;
                float sgn = cp ? -IS2 : IS2;
                int vof = ((r0 - 10) >> 1) * 128 + j2;
                c2q_col_pipe<19, -1, 26, 7>(acc,
                    pE + 0 * 16384, pE + 5 * 16384,
                    pO + 0 * 16384, pO + 5 * 16384, vof, sgn, g1);
            }
        } else if (role == 2) {
            if (lr < 82) {                        // t2 = col_g0(hl), bands 2,3
                ti = lr + 3;
                int cc = symidx(c0 + lr - 9, 256);
                int cp = cc & 1, j2 = cc >> 1;
                const float* pE = cp ? yhi : yhr;
                const float* pO = cp ? yhr : yhi;
                float sgn = cp ? -IS2 : IS2;
                int vof = ((r0 - 6) >> 1) * 128 + j2;
                c2q_col_pipe<13, 0, 22, 6>(acc,
                    pE + 2 * 16384, pE + 3 * 16384,
                    pO + 2 * 16384, pO + 3 * 16384, vof, sgn, g0);
            }
        } else {
            if (lr < 76) {                        // t3 = col_g2(hh), bands 1,4
                ti = lr + 6;
                int cc = symidx(c0 + lr - 6, 256);
                int cp = cc & 1, j2 = cc >> 1;
                const float* pE = cp ? yhi : yhr;
                const float* pO = cp ? yhr : yhi;
                float sgn = cp ? -IS2 : IS2;
                int vof = ((r0 - 6) >> 1) * 128 + j2;
                c2q_col_pipe<13, 0, 22, 6>(acc,
                    pE + 1 * 16384, pE + 4 * 16384,
                    pO + 1 * 16384, pO + 4 * 16384, vof, sgn, g2);
            }
        }
    } else {
        // ---------- border stage 1 (r1 path, handles row reflection) ----------
        if (role == 0) {
            if (lr < 76) {
                ti = lr + 6;
                int cc = symidx(c0 + ti - 12, 256);
                col13_yl(acc, ylp, g0, r0, cc);
            }
        } else if (role == 1) {
            if (lr < 76) {
                ti = lr + 6;
                int cc = symidx(c0 + ti - 12, 256);
                col19_c2q(acc, yhr, yhi, g1, r0, cc);
            }
        } else if (role == 2) {
            if (lr < 82) {
                ti = lr + 3;
                int cc = symidx(c0 + ti - 12, 256);
                col13_c2q(acc, yhr, yhi, 2, 3, g0, r0, cc);
            }
        } else {
            if (lr < 76) {
                ti = lr + 6;
                int cc = symidx(c0 + ti - 12, 256);
                col13_c2q(acc, yhr, yhi, 1, 4, g2, r0, cc);
            }
        }
    }

    // direct writers: role0 -> sU[0], role2 -> sU[1], role3 -> sU[2]
    if (ti >= 0 && role != 1) {
        const int bi = (role == 0) ? 0 : (role == 2 ? 1 : 2);
        #pragma unroll
        for (int ro = 0; ro < 32; ++ro) sU[bi][ro][ti] = acc[ro];
    }
    __syncthreads();

    // deferred add: lh accumulates into t1 buffer (2 waves only)
    if (role == 1 && ti >= 0) {
        #pragma unroll
        for (int ro = 0; ro < 32; ++ro) sU[0][ro][ti] += acc[ro];
    }

    // meanwhile all waves prefetch w2/w3 (untouched buffers)
    const int cg = tid & 15;
    const int r2 = tid >> 4;
    const int cb = 4 * cg;

    float w2[28];
    #pragma unroll
    for (int k = 0; k < 14; ++k) {
        float2 a = *(const float2*)&sU[1][r2][cb + 2 * k];
        w2[2*k] = a.x; w2[2*k+1] = a.y;
    }
    float w3[20];
    #pragma unroll
    for (int k = 0; k < 10; ++k) {
        float2 a = *(const float2*)&sU[2][r2][cb + 4 + 2 * k];
        w3[2*k] = a.x; w3[2*k+1] = a.y;
    }
    __syncthreads();

    float w1[20];
    #pragma unroll
    for (int k = 0; k < 10; ++k) {
        float2 a = *(const float2*)&sU[0][r2][cb + 4 + 2 * k];
        w1[2*k] = a.x; w1[2*k+1] = a.y;
    }

    float4 res;
    float* op = (float*)&res;
    #pragma unroll
    for (int q = 0; q < 4; ++q) {
        float s = 0.0f;
        #pragma unroll
        for (int j = 0; j < 13; ++j) s = fmaf(g0[j], w1[q + 14 - j], s);
        #pragma unroll
        for (int j = 0; j < 19; ++j) s = fmaf(g1[j], w2[q + 21 - j], s);
        #pragma unroll
        for (int j = 0; j < 13; ++j) s = fmaf(g2[j], w3[q + 14 - j], s);
        op[q] = s;
    }
    *(float4*)&out[(size_t)plane * 65536 + (size_t)(r0 + r2) * 256 + (c0 + cb)] = res;
}

extern "C" void kernel_launch(void* const* d_in, const int* in_sizes, int n_in,
                              void* d_out, int out_size, void* d_ws, size_t ws_size,
                              hipStream_t stream) {
    const float* Yl  = (const float*)d_in[0];
    const float* Yhr = (const float*)d_in[1];
    const float* Yhi = (const float*)d_in[2];
    const float* g0  = (const float*)d_in[3];
    const float* g1  = (const float*)d_in[4];
    const float* g2  = (const float*)d_in[5];
    float* out = (float*)d_out;

    dim3 grid(16384, 1, 1);
    dim3 block(512, 1, 1);
    dtcwt_inv<<<grid, block, 0, stream>>>(Yl, Yhr, Yhi, g0, g1, g2, out);
}

// Round 10
// 312.639 us; speedup vs baseline: 3.0372x; 3.0372x over previous
//
#include <hip/hip_runtime.h>

#define PW 90
#define IS2 0.70710678118654752f

__device__ __forceinline__ int symidx(int t, int n) {
    t = (t < 0) ? (-1 - t) : t;
    return (t >= n) ? (2 * n - 1 - t) : t;
}

#define SB() __builtin_amdgcn_sched_barrier(0)

// ================= border-path helpers (r1, proven) =================
__device__ __forceinline__ void col13_yl(
    float (&acc)[32], const float* __restrict__ ylp,
    const float* __restrict__ taps, int r0, int cc)
{
    #pragma unroll
    for (int pi = 0; pi < 44; ++pi) {
        int rr = symidx(r0 - 6 + pi, 256);
        float v = ylp[rr * 256 + cc];
        #pragma unroll
        for (int j = 0; j < 13; ++j) {
            int ro = pi + j - 12;
            if (ro >= 0 && ro < 32) acc[ro] = fmaf(taps[j], v, acc[ro]);
        }
    }
}

__device__ __forceinline__ void col13_c2q(
    float (&acc)[32], const float* __restrict__ yhr, const float* __restrict__ yhi,
    int bA, int bB, const float* __restrict__ taps, int r0, int cc)
{
    const int cp = cc & 1;
    const int j2 = cc >> 1;
    #pragma unroll
    for (int pi = 0; pi < 44; ++pi) {
        int rr = symidx(r0 - 6 + pi, 256);
        int rp = rr & 1;
        int i2 = rr >> 1;
        const float* base = (((rp ^ cp) != 0) ? yhi : yhr) + (i2 * 128 + j2);
        float A  = base[bA * 16384];
        float Bv = base[bB * 16384];
        float vA = (rp & cp)       ? -A  : A;
        float vB = (rp & (cp ^ 1)) ? -Bv : Bv;
        float v = (vA + vB) * IS2;
        #pragma unroll
        for (int j = 0; j < 13; ++j) {
            int ro = pi + j - 12;
            if (ro >= 0 && ro < 32) acc[ro] = fmaf(taps[j], v, acc[ro]);
        }
    }
}

__device__ __forceinline__ void col19_c2q(
    float (&acc)[32], const float* __restrict__ yhr, const float* __restrict__ yhi,
    const float* __restrict__ taps, int r0, int cc)
{
    const int bA = 0, bB = 5;
    const int cp = cc & 1;
    const int j2 = cc >> 1;
    #pragma unroll
    for (int pi = 0; pi < 50; ++pi) {
        int rr = symidx(r0 - 9 + pi, 256);
        int rp = rr & 1;
        int i2 = rr >> 1;
        const float* base = (((rp ^ cp) != 0) ? yhi : yhr) + (i2 * 128 + j2);
        float A  = base[bA * 16384];
        float Bv = base[bB * 16384];
        float vA = (rp & cp)       ? -A  : A;
        float vB = (rp & (cp ^ 1)) ? -Bv : Bv;
        float v = (vA + vB) * IS2;
        #pragma unroll
        for (int j = 0; j < 19; ++j) {
            int ro = pi + j - 18;
            if (ro >= 0 && ro < 32) acc[ro] = fmaf(taps[j], v, acc[ro]);
        }
    }
}

// ================= interior pipelined helpers (r8, proven) =================
template<int NU>
__device__ __forceinline__ void load_pairs(float (&buf)[28],
    const float* __restrict__ pEA, const float* __restrict__ pEB,
    const float* __restrict__ pOA, const float* __restrict__ pOB,
    int vof)
{
    #pragma unroll
    for (int u = 0; u < NU; ++u) {
        buf[4*u+0] = pEA[vof + u * 128];
        buf[4*u+1] = pEB[vof + u * 128];
        buf[4*u+2] = pOA[vof + u * 128];
        buf[4*u+3] = pOB[vof + u * 128];
    }
}

template<int L, int EPI0, int UB, int NU>
__device__ __forceinline__ void consume_pairs(float (&acc)[32], const float (&buf)[28],
                                              float sgn, const float* __restrict__ taps)
{
    #pragma unroll
    for (int u = 0; u < NU; ++u) {
        float ve = (buf[4*u+0] + buf[4*u+1]) * IS2;
        float vo = (buf[4*u+2] - buf[4*u+3]) * sgn;
        const int pi = EPI0 + 2 * (UB + u);
        #pragma unroll
        for (int j = 0; j < L; ++j) {
            int ro = pi + j - (L - 1);
            if (ro >= 0 && ro < 32) acc[ro] = fmaf(taps[j], ve, acc[ro]);
        }
        #pragma unroll
        for (int j = 0; j < L; ++j) {
            int ro = pi + 1 + j - (L - 1);
            if (ro >= 0 && ro < 32) acc[ro] = fmaf(taps[j], vo, acc[ro]);
        }
    }
}

template<int NT>
__device__ __forceinline__ void load_rows(float (&buf)[11], const float* __restrict__ p, int t0)
{
    #pragma unroll
    for (int t = 0; t < NT; ++t) buf[t] = p[(t0 + t) * 256];
}

template<int TB, int NT>
__device__ __forceinline__ void consume_rows(float (&acc)[32], const float (&buf)[11],
                                             const float* __restrict__ taps)
{
    #pragma unroll
    for (int t = 0; t < NT; ++t) {
        float v = buf[t];
        const int pi = TB + t;
        #pragma unroll
        for (int j = 0; j < 13; ++j) {
            int ro = pi + j - 12;
            if (ro >= 0 && ro < 32) acc[ro] = fmaf(taps[j], v, acc[ro]);
        }
    }
}

template<int L, int EPI0, int NPT, int C>
__device__ __forceinline__ void c2q_col_pipe(
    float (&acc)[32],
    const float* __restrict__ pEA, const float* __restrict__ pEB,
    const float* __restrict__ pOA, const float* __restrict__ pOB,
    int vof, float sgn, const float* __restrict__ taps)
{
    float bufA[28], bufB[28];
    constexpr int R = NPT - 3 * C;
    load_pairs<C>(bufA, pEA, pEB, pOA, pOB, vof);
    SB();
    load_pairs<C>(bufB, pEA, pEB, pOA, pOB, vof + C * 128);
    SB();
    consume_pairs<L, EPI0, 0, C>(acc, bufA, sgn, taps);
    SB();
    load_pairs<C>(bufA, pEA, pEB, pOA, pOB, vof + 2 * C * 128);
    SB();
    consume_pairs<L, EPI0, C, C>(acc, bufB, sgn, taps);
    SB();
    load_pairs<R>(bufB, pEA, pEB, pOA, pOB, vof + 3 * C * 128);
    SB();
    consume_pairs<L, EPI0, 2 * C, C>(acc, bufA, sgn, taps);
    SB();
    consume_pairs<L, EPI0, 3 * C, R>(acc, bufB, sgn, taps);
}

extern "C" __global__ __launch_bounds__(512, 4) void dtcwt_inv(
    const float* __restrict__ Yl, const float* __restrict__ Yhr,
    const float* __restrict__ Yhi,
    const float* __restrict__ g0, const float* __restrict__ g1,
    const float* __restrict__ g2, float* __restrict__ out)
{
    // sU[0] = t1a (+t1b added after barrier1), sU[1] = t2 (hl), sU[2] = t3 (hh)
    __shared__ __align__(16) float sU[3][32][PW];   // 34560 B -> 4 blocks/CU

    const int tid = threadIdx.x;
    // bijective XCD swizzle: 16384 = 8 x 2048
    const int wg  = blockIdx.x;
    const int swz = (wg & 7) * 2048 + (wg >> 3);
    const int plane = swz >> 5;
    const int bt = swz & 31;
    const int bx = bt & 3;
    const int by = bt >> 2;
    const int r0 = by * 32;
    const int c0 = bx * 64;

    const float* ylp = Yl  + (size_t)plane * 65536;
    const float* yhr = Yhr + (size_t)plane * 6 * 16384;
    const float* yhi = Yhi + (size_t)plane * 6 * 16384;

    const bool rowInterior = (by >= 1) && (by <= 6);

    const int role = tid >> 7;
    const int lr   = tid & 127;

    float acc[32];
    #pragma unroll
    for (int i = 0; i < 32; ++i) acc[i] = 0.0f;
    int ti = -1;

    if (rowInterior) {
        if (role == 0) {
            if (lr < 76) {
                ti = lr + 6;
                int cc = symidx(c0 + lr - 6, 256);
                const float* p = ylp + (r0 - 6) * 256 + cc;
                float bufA[11], bufB[11];
                load_rows<11>(bufA, p, 0);
                SB();
                load_rows<11>(bufB, p, 11);
                SB();
                consume_rows<0, 11>(acc, bufA, g0);
                SB();
                load_rows<11>(bufA, p, 22);
                SB();
                consume_rows<11, 11>(acc, bufB, g0);
                SB();
                load_rows<11>(bufB, p, 33);
                SB();
                consume_rows<22, 11>(acc, bufA, g0);
                SB();
                consume_rows<33, 11>(acc, bufB, g0);
            }
        } else if (role == 1) {
            if (lr < 76) {                        // t1b = col_g1(lh), bands 0,5
                ti = lr + 6;
                int cc = symidx(c0 + lr - 6, 256);
                int cp = cc & 1, j2 = cc >> 1;
                const float* pE = cp ? yhi : yhr;
                const float* pO = cp ? yhr : yhi;
                float sgn = cp ? -IS2 : IS2;
                int vof = ((r0 - 10) >> 1) * 128 + j2;
                c2q_col_pipe<19, -1, 26, 7>(acc,
                    pE + 0 * 16384, pE + 5 * 16384,
                    pO + 0 * 16384, pO + 5 * 16384, vof, sgn, g1);
            }
        } else if (role == 2) {
            if (lr < 82) {                        // t2 = col_g0(hl), bands 2,3
                ti = lr + 3;
                int cc = symidx(c0 + lr - 9, 256);
                int cp = cc & 1, j2 = cc >> 1;
                const float* pE = cp ? yhi : yhr;
                const float* pO = cp ? yhr : yhi;
                float sgn = cp ? -IS2 : IS2;
                int vof = ((r0 - 6) >> 1) * 128 + j2;
                c2q_col_pipe<13, 0, 22, 6>(acc,
                    pE + 2 * 16384, pE + 3 * 16384,
                    pO + 2 * 16384, pO + 3 * 16384, vof, sgn, g0);
            }
        } else {
            if (lr < 76) {                        // t3 = col_g2(hh), bands 1,4
                ti = lr + 6;
                int cc = symidx(c0 + lr - 6, 256);
                int cp = cc & 1, j2 = cc >> 1;
                const float* pE = cp ? yhi : yhr;
                const float* pO = cp ? yhr : yhi;
                float sgn = cp ? -IS2 : IS2;
                int vof = ((r0 - 6) >> 1) * 128 + j2;
                c2q_col_pipe<13, 0, 22, 6>(acc,
                    pE + 1 * 16384, pE + 4 * 16384,
                    pO + 1 * 16384, pO + 4 * 16384, vof, sgn, g2);
            }
        }
    } else {
        // ---------- border stage 1 (r1 path, handles row reflection) ----------
        if (role == 0) {
            if (lr < 76) {
                ti = lr + 6;
                int cc = symidx(c0 + ti - 12, 256);
                col13_yl(acc, ylp, g0, r0, cc);
            }
        } else if (role == 1) {
            if (lr < 76) {
                ti = lr + 6;
                int cc = symidx(c0 + ti - 12, 256);
                col19_c2q(acc, yhr, yhi, g1, r0, cc);
            }
        } else if (role == 2) {
            if (lr < 82) {
                ti = lr + 3;
                int cc = symidx(c0 + ti - 12, 256);
                col13_c2q(acc, yhr, yhi, 2, 3, g0, r0, cc);
            }
        } else {
            if (lr < 76) {
                ti = lr + 6;
                int cc = symidx(c0 + ti - 12, 256);
                col13_c2q(acc, yhr, yhi, 1, 4, g2, r0, cc);
            }
        }
    }

    // direct writers: role0 -> sU[0], role2 -> sU[1], role3 -> sU[2]
    if (ti >= 0 && role != 1) {
        const int bi = (role == 0) ? 0 : (role == 2 ? 1 : 2);
        #pragma unroll
        for (int ro = 0; ro < 32; ++ro) sU[bi][ro][ti] = acc[ro];
    }
    __syncthreads();

    // deferred add: lh accumulates into t1 buffer (2 waves only)
    if (role == 1 && ti >= 0) {
        #pragma unroll
        for (int ro = 0; ro < 32; ++ro) sU[0][ro][ti] += acc[ro];
    }

    // meanwhile all waves prefetch w2/w3 (untouched buffers)
    const int cg = tid & 15;
    const int r2 = tid >> 4;
    const int cb = 4 * cg;

    float w2[28];
    #pragma unroll
    for (int k = 0; k < 14; ++k) {
        float2 a = *(const float2*)&sU[1][r2][cb + 2 * k];
        w2[2*k] = a.x; w2[2*k+1] = a.y;
    }
    float w3[20];
    #pragma unroll
    for (int k = 0; k < 10; ++k) {
        float2 a = *(const float2*)&sU[2][r2][cb + 4 + 2 * k];
        w3[2*k] = a.x; w3[2*k+1] = a.y;
    }
    __syncthreads();

    float w1[20];
    #pragma unroll
    for (int k = 0; k < 10; ++k) {
        float2 a = *(const float2*)&sU[0][r2][cb + 4 + 2 * k];
        w1[2*k] = a.x; w1[2*k+1] = a.y;
    }

    float4 res;
    float* op = (float*)&res;
    #pragma unroll
    for (int q = 0; q < 4; ++q) {
        float s = 0.0f;
        #pragma unroll
        for (int j = 0; j < 13; ++j) s = fmaf(g0[j], w1[q + 14 - j], s);
        #pragma unroll
        for (int j = 0; j < 19; ++j) s = fmaf(g1[j], w2[q + 21 - j], s);
        #pragma unroll
        for (int j = 0; j < 13; ++j) s = fmaf(g2[j], w3[q + 14 - j], s);
        op[q] = s;
    }
    *(float4*)&out[(size_t)plane * 65536 + (size_t)(r0 + r2) * 256 + (c0 + cb)] = res;
}

extern "C" void kernel_launch(void* const* d_in, const int* in_sizes, int n_in,
                              void* d_out, int out_size, void* d_ws, size_t ws_size,
                              hipStream_t stream) {
    const float* Yl  = (const float*)d_in[0];
    const float* Yhr = (const float*)d_in[1];
    const float* Yhi = (const float*)d_in[2];
    const float* g0  = (const float*)d_in[3];
    const float* g1  = (const float*)d_in[4];
    const float* g2  = (const float*)d_in[5];
    float* out = (float*)d_out;

    dim3 grid(16384, 1, 1);
    dim3 block(512, 1, 1);
    dtcwt_inv<<<grid, block, 0, stream>>>(Yl, Yhr, Yhi, g0, g1, g2, out);
}